// Round 1
// baseline (929.875 us; speedup 1.0000x reference)
//
#include <hip/hip_runtime.h>
#include <cstddef>

#define B_ 16
#define C_ 256
#define C2_ 512
#define L_ 8192
#define EPS_ 1e-5f

// ---------------------------------------------------------------------------
// K1: LayerNorm stats over channel dim per (b,l).  mu/rs: [B*L]
// ---------------------------------------------------------------------------
__global__ __launch_bounds__(256) void ln_stats_k(const float* __restrict__ x,
                                                  float* __restrict__ mu,
                                                  float* __restrict__ rs) {
  int idx = blockIdx.x * 256 + threadIdx.x;   // b*L + l
  int b = idx >> 13;                          // L = 8192 = 2^13
  int l = idx & (L_ - 1);
  const float* xp = x + (size_t)b * C_ * L_ + l;
  float s = 0.f, ss = 0.f;
#pragma unroll 8
  for (int c = 0; c < C_; ++c) {
    float v = xp[(size_t)c * L_];
    s += v;
    ss += v * v;
  }
  float m = s * (1.f / C_);
  float var = ss * (1.f / C_) - m * m;
  mu[idx] = m;
  rs[idx] = rsqrtf(var + EPS_);
}

// ---------------------------------------------------------------------------
// K2: pw1 GEMM with LN fused into B staging.
// t1[b,o,l] = b1[o] + sum_c w1[o,c] * ((x[b,c,l]-mu)*rs*gamma[c]+beta[c])
// Tile: BM=128 (o), BN=128 (l), BK=8; 256 threads; 8x8 micro-tile.
// ---------------------------------------------------------------------------
__global__ __launch_bounds__(256) void pw1_gemm_k(
    const float* __restrict__ x, const float* __restrict__ mu,
    const float* __restrict__ rs, const float* __restrict__ gamma,
    const float* __restrict__ beta, const float* __restrict__ w1,
    const float* __restrict__ b1, float* __restrict__ t1) {
  __shared__ float As[8][132];   // [k][m], padded to kill staging bank conflicts
  __shared__ float Bs[8][128];   // [k][n]
  const int b = blockIdx.z;
  const int o0 = blockIdx.x * 128;
  const int l0 = blockIdx.y * 128;
  const int tid = threadIdx.x;
  const int tx = tid & 15, ty = tid >> 4;

  const float* xb = x + (size_t)b * C_ * L_;
  const int ar = tid >> 1;           // A row (m) 0..127
  const int ac = (tid & 1) * 4;      // A col (k) 0 or 4
  const int bk = tid >> 5;           // B row (k) 0..7
  const int bc = (tid & 31) * 4;     // B col (n) 0..124

  const float4 mu4 = *(const float4*)(mu + (size_t)b * L_ + l0 + bc);
  const float4 rs4 = *(const float4*)(rs + (size_t)b * L_ + l0 + bc);

  float acc[8][8] = {};

  float4 a4 = *(const float4*)(w1 + (size_t)(o0 + ar) * C_ + ac);
  float4 xv = *(const float4*)(xb + (size_t)bk * L_ + l0 + bc);
  float ga = gamma[bk], be = beta[bk];

  for (int k0 = 0; k0 < C_; k0 += 8) {
    __syncthreads();
    As[ac + 0][ar] = a4.x;
    As[ac + 1][ar] = a4.y;
    As[ac + 2][ar] = a4.z;
    As[ac + 3][ar] = a4.w;
    float4 yv;
    yv.x = (xv.x - mu4.x) * rs4.x * ga + be;
    yv.y = (xv.y - mu4.y) * rs4.y * ga + be;
    yv.z = (xv.z - mu4.z) * rs4.z * ga + be;
    yv.w = (xv.w - mu4.w) * rs4.w * ga + be;
    *(float4*)&Bs[bk][bc] = yv;
    __syncthreads();

    // prefetch next K-tile (overlap global latency with compute)
    int kn = (k0 + 8 < C_) ? k0 + 8 : 0;
    a4 = *(const float4*)(w1 + (size_t)(o0 + ar) * C_ + kn + ac);
    int cn = kn + bk;
    xv = *(const float4*)(xb + (size_t)cn * L_ + l0 + bc);
    ga = gamma[cn];
    be = beta[cn];

#pragma unroll
    for (int k = 0; k < 8; ++k) {
      float a[8], bb[8];
      *(float4*)&a[0] = *(const float4*)&As[k][ty * 8];
      *(float4*)&a[4] = *(const float4*)&As[k][ty * 8 + 4];
      *(float4*)&bb[0] = *(const float4*)&Bs[k][tx * 8];
      *(float4*)&bb[4] = *(const float4*)&Bs[k][tx * 8 + 4];
#pragma unroll
      for (int i = 0; i < 8; ++i)
#pragma unroll
        for (int j = 0; j < 8; ++j) acc[i][j] += a[i] * bb[j];
    }
  }

  for (int i = 0; i < 8; ++i) {
    int o = o0 + ty * 8 + i;
    float bias = b1[o];
    float* dst = t1 + ((size_t)b * C2_ + o) * L_ + l0 + tx * 8;
    float4 v0 = make_float4(acc[i][0] + bias, acc[i][1] + bias,
                            acc[i][2] + bias, acc[i][3] + bias);
    float4 v1 = make_float4(acc[i][4] + bias, acc[i][5] + bias,
                            acc[i][6] + bias, acc[i][7] + bias);
    *(float4*)dst = v0;
    *((float4*)dst + 1) = v1;
  }
}

// ---------------------------------------------------------------------------
// K3: depthwise conv(k=3,pad=1) + bias + SimpleGate, IN-PLACE over t1's first
// half, plus per-(b,c) mean over L for SCA pooling.
// One block owns one (b,c) row entirely -> no cross-block read/write hazard,
// no atomics.  Reads before an internal barrier, writes after.
// ---------------------------------------------------------------------------
__global__ __launch_bounds__(256) void dwgate_k(float* __restrict__ t1,
                                                float* __restrict__ p,
                                                const float* __restrict__ wd,
                                                const float* __restrict__ bd) {
  const int c = blockIdx.x;   // 0..255
  const int b = blockIdx.y;
  float* r1 = t1 + ((size_t)b * C2_ + c) * L_;
  float* r2 = t1 + ((size_t)b * C2_ + c + C_) * L_;
  const float w10 = wd[c * 3 + 0], w11 = wd[c * 3 + 1], w12 = wd[c * 3 + 2];
  const float w20 = wd[(c + C_) * 3 + 0], w21 = wd[(c + C_) * 3 + 1],
              w22 = wd[(c + C_) * 3 + 2];
  const float bd1 = bd[c], bd2 = bd[c + C_];
  const int tid = threadIdx.x;

  float gv[8][4];
  float sum = 0.f;
#pragma unroll
  for (int it = 0; it < 8; ++it) {
    int l = it * 1024 + tid * 4;
    float4 v1 = *(const float4*)(r1 + l);
    float4 v2 = *(const float4*)(r2 + l);
    float v1m = (l == 0) ? 0.f : r1[l - 1];
    float v1p = (l == L_ - 4) ? 0.f : r1[l + 4];
    float v2m = (l == 0) ? 0.f : r2[l - 1];
    float v2p = (l == L_ - 4) ? 0.f : r2[l + 4];
    float d1[4], d2[4];
    d1[0] = bd1 + w10 * v1m + w11 * v1.x + w12 * v1.y;
    d1[1] = bd1 + w10 * v1.x + w11 * v1.y + w12 * v1.z;
    d1[2] = bd1 + w10 * v1.y + w11 * v1.z + w12 * v1.w;
    d1[3] = bd1 + w10 * v1.z + w11 * v1.w + w12 * v1p;
    d2[0] = bd2 + w20 * v2m + w21 * v2.x + w22 * v2.y;
    d2[1] = bd2 + w20 * v2.x + w21 * v2.y + w22 * v2.z;
    d2[2] = bd2 + w20 * v2.y + w21 * v2.z + w22 * v2.w;
    d2[3] = bd2 + w20 * v2.z + w21 * v2.w + w22 * v2p;
#pragma unroll
    for (int j = 0; j < 4; ++j) {
      gv[it][j] = d1[j] * d2[j];
      sum += gv[it][j];
    }
  }
  __syncthreads();   // all reads of this row complete before in-place writes
#pragma unroll
  for (int it = 0; it < 8; ++it) {
    int l = it * 1024 + tid * 4;
    *(float4*)(r1 + l) =
        make_float4(gv[it][0], gv[it][1], gv[it][2], gv[it][3]);
  }
  __shared__ float red[256];
  red[tid] = sum;
  __syncthreads();
  for (int s = 128; s > 0; s >>= 1) {
    if (tid < s) red[tid] += red[tid + s];
    __syncthreads();
  }
  if (tid == 0) p[b * C_ + c] = red[0] * (1.f / L_);
}

// ---------------------------------------------------------------------------
// K4: SCA weights: wsca[b,o] = sigmoid(sum_c p[b,c]*ws[o,c] + bs[o])
// ---------------------------------------------------------------------------
__global__ __launch_bounds__(256) void sca_k(const float* __restrict__ p,
                                             const float* __restrict__ ws,
                                             const float* __restrict__ bs,
                                             float* __restrict__ wsca) {
  int b = blockIdx.x, o = threadIdx.x;
  __shared__ float pp[C_];
  pp[o] = p[b * C_ + o];
  __syncthreads();
  float acc = bs[o];
  const float* wr = ws + (size_t)o * C_;
#pragma unroll 4
  for (int c = 0; c < C_; ++c) acc += pp[c] * wr[c];
  wsca[b * C_ + o] = 1.f / (1.f + expf(-acc));
}

// ---------------------------------------------------------------------------
// K5: pw2 GEMM. out[b,o,l] = x[b,o,l] + b2[o] + sum_c w2[o,c]*(g[b,c,l]*wsca[b,c])
// g lives in-place in t1 channels 0..C-1.
// ---------------------------------------------------------------------------
__global__ __launch_bounds__(256) void pw2_gemm_k(
    const float* __restrict__ t1, const float* __restrict__ wsca,
    const float* __restrict__ w2, const float* __restrict__ b2,
    const float* __restrict__ x, float* __restrict__ out) {
  __shared__ float As[8][132];
  __shared__ float Bs[8][128];
  const int b = blockIdx.z;
  const int o0 = blockIdx.x * 128;
  const int l0 = blockIdx.y * 128;
  const int tid = threadIdx.x;
  const int tx = tid & 15, ty = tid >> 4;

  const float* gb = t1 + (size_t)b * C2_ * L_;
  const float* wb = wsca + b * C_;
  const int ar = tid >> 1;
  const int ac = (tid & 1) * 4;
  const int bk = tid >> 5;
  const int bc = (tid & 31) * 4;

  float acc[8][8] = {};

  float4 a4 = *(const float4*)(w2 + (size_t)(o0 + ar) * C_ + ac);
  float4 gvv = *(const float4*)(gb + (size_t)bk * L_ + l0 + bc);
  float wv = wb[bk];

  for (int k0 = 0; k0 < C_; k0 += 8) {
    __syncthreads();
    As[ac + 0][ar] = a4.x;
    As[ac + 1][ar] = a4.y;
    As[ac + 2][ar] = a4.z;
    As[ac + 3][ar] = a4.w;
    *(float4*)&Bs[bk][bc] =
        make_float4(gvv.x * wv, gvv.y * wv, gvv.z * wv, gvv.w * wv);
    __syncthreads();

    int kn = (k0 + 8 < C_) ? k0 + 8 : 0;
    a4 = *(const float4*)(w2 + (size_t)(o0 + ar) * C_ + kn + ac);
    gvv = *(const float4*)(gb + (size_t)(kn + bk) * L_ + l0 + bc);
    wv = wb[kn + bk];

#pragma unroll
    for (int k = 0; k < 8; ++k) {
      float a[8], bb[8];
      *(float4*)&a[0] = *(const float4*)&As[k][ty * 8];
      *(float4*)&a[4] = *(const float4*)&As[k][ty * 8 + 4];
      *(float4*)&bb[0] = *(const float4*)&Bs[k][tx * 8];
      *(float4*)&bb[4] = *(const float4*)&Bs[k][tx * 8 + 4];
#pragma unroll
      for (int i = 0; i < 8; ++i)
#pragma unroll
        for (int j = 0; j < 8; ++j) acc[i][j] += a[i] * bb[j];
    }
  }

  for (int i = 0; i < 8; ++i) {
    int o = o0 + ty * 8 + i;
    float bias = b2[o];
    const float* xs = x + ((size_t)b * C_ + o) * L_ + l0 + tx * 8;
    float4 x0 = *(const float4*)xs;
    float4 x1 = *((const float4*)xs + 1);
    float* dst = out + ((size_t)b * C_ + o) * L_ + l0 + tx * 8;
    *(float4*)dst = make_float4(acc[i][0] + bias + x0.x, acc[i][1] + bias + x0.y,
                                acc[i][2] + bias + x0.z, acc[i][3] + bias + x0.w);
    *((float4*)dst + 1) =
        make_float4(acc[i][4] + bias + x1.x, acc[i][5] + bias + x1.y,
                    acc[i][6] + bias + x1.z, acc[i][7] + bias + x1.w);
  }
}

// ---------------------------------------------------------------------------
// Workspace layout (floats):
//   t1   : B*C2*L            = 67,108,864   (256 MiB)  -- pw1 out, gate in-place
//   mu   : B*L               = 131,072
//   rs   : B*L               = 131,072
//   p    : B*C               = 4,096
//   wsca : B*C               = 4,096
// total ~= 257 MiB
// ---------------------------------------------------------------------------
extern "C" void kernel_launch(void* const* d_in, const int* in_sizes, int n_in,
                              void* d_out, int out_size, void* d_ws,
                              size_t ws_size, hipStream_t stream) {
  const float* x = (const float*)d_in[0];
  const float* gamma = (const float*)d_in[1];
  const float* beta = (const float*)d_in[2];
  const float* w1 = (const float*)d_in[3];
  const float* b1 = (const float*)d_in[4];
  const float* wd = (const float*)d_in[5];
  const float* bd = (const float*)d_in[6];
  const float* ws = (const float*)d_in[7];
  const float* bs = (const float*)d_in[8];
  const float* w2 = (const float*)d_in[9];
  const float* b2 = (const float*)d_in[10];
  float* out = (float*)d_out;

  float* t1 = (float*)d_ws;
  float* mu = t1 + (size_t)B_ * C2_ * L_;
  float* rs = mu + (size_t)B_ * L_;
  float* p = rs + (size_t)B_ * L_;
  float* wsca = p + B_ * C_;

  ln_stats_k<<<dim3(B_ * L_ / 256), 256, 0, stream>>>(x, mu, rs);
  pw1_gemm_k<<<dim3(C2_ / 128, L_ / 128, B_), 256, 0, stream>>>(
      x, mu, rs, gamma, beta, w1, b1, t1);
  dwgate_k<<<dim3(C_, B_), 256, 0, stream>>>(t1, p, wd, bd);
  sca_k<<<dim3(B_), 256, 0, stream>>>(p, ws, bs, wsca);
  pw2_gemm_k<<<dim3(C_ / 128, L_ / 128, B_), 256, 0, stream>>>(
      t1, wsca, w2, b2, x, out);
}

// Round 2
// 615.833 us; speedup vs baseline: 1.5099x; 1.5099x over previous
//
#include <hip/hip_runtime.h>
#include <cstddef>

#define B_ 16
#define C_ 256
#define C2_ 512
#define L_ 8192
#define EPS_ 1e-5f
#define BK_ 32
#define LDK_ 40   // 32 + 8 pad (keeps 16B alignment, balances bank start-slots)

typedef __attribute__((ext_vector_type(8))) short bf16x8;  // 8 bf16 = 4 VGPR
typedef __attribute__((ext_vector_type(4))) float f32x4;

static __device__ __forceinline__ short f2bf(float f) {  // RTNE float->bf16 bits
  unsigned u = __builtin_bit_cast(unsigned, f);
  unsigned r = (u + 0x7fffu + ((u >> 16) & 1u)) >> 16;
  return (short)r;
}
static __device__ __forceinline__ float bf2f(short h) {
  unsigned u = ((unsigned)(unsigned short)h) << 16;
  return __builtin_bit_cast(float, u);
}

// ---------------------------------------------------------------------------
// K0: split w1/w2 into bf16 hi/lo pairs (3-term bf16x3 fp32 emulation).
// ---------------------------------------------------------------------------
__global__ __launch_bounds__(256) void wprep_k(
    const float* __restrict__ w1, const float* __restrict__ w2,
    short* __restrict__ w1h, short* __restrict__ w1l,
    short* __restrict__ w2h, short* __restrict__ w2l) {
  int i = blockIdx.x * 256 + threadIdx.x;
  if (i < C2_ * C_) {
    float f = w1[i];
    short h = f2bf(f);
    w1h[i] = h;
    w1l[i] = f2bf(f - bf2f(h));
  } else {
    int j = i - C2_ * C_;
    float f = w2[j];
    short h = f2bf(f);
    w2h[j] = h;
    w2l[j] = f2bf(f - bf2f(h));
  }
}

// ---------------------------------------------------------------------------
// K1: LayerNorm stats per (b,l), float4-vectorized over l.
// ---------------------------------------------------------------------------
__global__ __launch_bounds__(128) void ln_stats_k(const float* __restrict__ x,
                                                  float* __restrict__ mu,
                                                  float* __restrict__ rs) {
  int idx = blockIdx.x * 128 + threadIdx.x;  // 0 .. B*L/4-1
  int b = idx >> 11;                          // L/4 = 2048
  int l4 = (idx & 2047) << 2;
  const float* xp = x + (size_t)b * C_ * L_ + l4;
  float4 s = make_float4(0.f, 0.f, 0.f, 0.f);
  float4 q = make_float4(0.f, 0.f, 0.f, 0.f);
#pragma unroll 4
  for (int c = 0; c < C_; ++c) {
    float4 v = *(const float4*)(xp + (size_t)c * L_);
    s.x += v.x; s.y += v.y; s.z += v.z; s.w += v.w;
    q.x += v.x * v.x; q.y += v.y * v.y; q.z += v.z * v.z; q.w += v.w * v.w;
  }
  const float inv = 1.f / C_;
  float4 m = make_float4(s.x * inv, s.y * inv, s.z * inv, s.w * inv);
  float4 r;
  r.x = rsqrtf(q.x * inv - m.x * m.x + EPS_);
  r.y = rsqrtf(q.y * inv - m.y * m.y + EPS_);
  r.z = rsqrtf(q.z * inv - m.z * m.z + EPS_);
  r.w = rsqrtf(q.w * inv - m.w * m.w + EPS_);
  *(float4*)(mu + b * L_ + l4) = m;
  *(float4*)(rs + b * L_ + l4) = r;
}

// ---------------------------------------------------------------------------
// K2: pw1 as bf16x3-split MFMA GEMM, LN fused into B staging.
// t1[b,o,l] = b1[o] + sum_c w1[o,c] * ((x[b,c,l]-mu)*rs*gamma[c]+beta[c])
// 128x128 tile, BK=32, 4 waves each owning a 64x64 subtile (4x4 frags of
// 16x16x32). A = w (pre-split bf16 hi/lo), B = y (split in-register).
// ---------------------------------------------------------------------------
__global__ __launch_bounds__(256, 2) void pw1_mfma_k(
    const float* __restrict__ x, const float* __restrict__ mu,
    const float* __restrict__ rs, const float* __restrict__ gamma,
    const float* __restrict__ beta, const short* __restrict__ w1h,
    const short* __restrict__ w1l, const float* __restrict__ b1,
    float* __restrict__ t1) {
  __shared__ short Ah[128 * LDK_], Al[128 * LDK_];
  __shared__ short Bh[128 * LDK_], Bl[128 * LDK_];
  const int g = blockIdx.x;
  // XCD-bijective swizzle: chunk g&7 -> XCD, o fastest within chunk.
  const int chunk = g & 7, ii = g >> 3;          // ii in 0..511
  const int ob = ii & 3;
  const int blid = chunk * 128 + (ii >> 2);      // 0..1023
  const int b = blid >> 6, lb = blid & 63;
  const int o0 = ob * 128, l0 = lb * 128;
  const int tid = threadIdx.x;
  const int ar = tid >> 1, akq = (tid & 1) * 16;   // A staging: 32 rows/wave, 32B each
  const int cq = (tid & 7) * 4, lq = (tid >> 3) * 4;  // B staging 4x4 block
  const int lane = tid & 63, wv = tid >> 6;
  const int mb = (wv >> 1) * 64, nb = (wv & 1) * 64;
  const int fr = lane & 15, fko = (lane >> 4) * 8;

  const float* xb = x + (size_t)b * C_ * L_ + l0 + lq;
  const float4 mu4 = *(const float4*)(mu + b * L_ + l0 + lq);
  const float4 rs4 = *(const float4*)(rs + b * L_ + l0 + lq);

  f32x4 acc[4][4];
#pragma unroll
  for (int i = 0; i < 4; ++i)
#pragma unroll
    for (int j = 0; j < 4; ++j) acc[i][j] = 0.f;

  for (int kc = 0; kc < C_; kc += BK_) {
    // ---- global loads into regs ----
    const size_t aw = (size_t)(o0 + ar) * C_ + kc + akq;
    float4 a_h0 = *(const float4*)(w1h + aw);
    float4 a_h1 = *(const float4*)(w1h + aw + 8);
    float4 a_l0 = *(const float4*)(w1l + aw);
    float4 a_l1 = *(const float4*)(w1l + aw + 8);
    float4 ga4 = *(const float4*)(gamma + kc + cq);
    float4 be4 = *(const float4*)(beta + kc + cq);
    float ga[4] = {ga4.x, ga4.y, ga4.z, ga4.w};
    float be[4] = {be4.x, be4.y, be4.z, be4.w};
    float yv[4][4];
#pragma unroll
    for (int i = 0; i < 4; ++i) {
      float4 xv = *(const float4*)(xb + (size_t)(kc + cq + i) * L_);
      yv[i][0] = (xv.x - mu4.x) * rs4.x * ga[i] + be[i];
      yv[i][1] = (xv.y - mu4.y) * rs4.y * ga[i] + be[i];
      yv[i][2] = (xv.z - mu4.z) * rs4.z * ga[i] + be[i];
      yv[i][3] = (xv.w - mu4.w) * rs4.w * ga[i] + be[i];
    }
    __syncthreads();  // previous compute phase done reading LDS
    *(float4*)&Ah[ar * LDK_ + akq] = a_h0;
    *(float4*)&Ah[ar * LDK_ + akq + 8] = a_h1;
    *(float4*)&Al[ar * LDK_ + akq] = a_l0;
    *(float4*)&Al[ar * LDK_ + akq + 8] = a_l1;
#pragma unroll
    for (int j = 0; j < 4; ++j) {   // transpose-write: B[l][c], hi/lo split
      short4 hh, ll;
      hh.x = f2bf(yv[0][j]); ll.x = f2bf(yv[0][j] - bf2f(hh.x));
      hh.y = f2bf(yv[1][j]); ll.y = f2bf(yv[1][j] - bf2f(hh.y));
      hh.z = f2bf(yv[2][j]); ll.z = f2bf(yv[2][j] - bf2f(hh.z));
      hh.w = f2bf(yv[3][j]); ll.w = f2bf(yv[3][j] - bf2f(hh.w));
      *(short4*)&Bh[(lq + j) * LDK_ + cq] = hh;
      *(short4*)&Bl[(lq + j) * LDK_ + cq] = ll;
    }
    __syncthreads();
    bf16x8 fah[4], fal[4], fbh[4], fbl[4];
#pragma unroll
    for (int f = 0; f < 4; ++f) {
      fah[f] = *(const bf16x8*)&Ah[(mb + f * 16 + fr) * LDK_ + fko];
      fal[f] = *(const bf16x8*)&Al[(mb + f * 16 + fr) * LDK_ + fko];
      fbh[f] = *(const bf16x8*)&Bh[(nb + f * 16 + fr) * LDK_ + fko];
      fbl[f] = *(const bf16x8*)&Bl[(nb + f * 16 + fr) * LDK_ + fko];
    }
#pragma unroll
    for (int mf = 0; mf < 4; ++mf)
#pragma unroll
      for (int nf = 0; nf < 4; ++nf) {
        f32x4 c = acc[mf][nf];
        c = __builtin_amdgcn_mfma_f32_16x16x32_bf16(fah[mf], fbh[nf], c, 0, 0, 0);
        c = __builtin_amdgcn_mfma_f32_16x16x32_bf16(fah[mf], fbl[nf], c, 0, 0, 0);
        c = __builtin_amdgcn_mfma_f32_16x16x32_bf16(fal[mf], fbh[nf], c, 0, 0, 0);
        acc[mf][nf] = c;
      }
  }
  // epilogue: C/D frag: col = lane&15 (l), row = (lane>>4)*4 + reg (o)
#pragma unroll
  for (int mf = 0; mf < 4; ++mf) {
    const int orow = o0 + mb + mf * 16 + ((lane >> 4) << 2);
    const float4 bv = *(const float4*)(b1 + orow);
    float* base = t1 + ((size_t)b * C2_ + orow) * L_ + l0 + nb + fr;
#pragma unroll
    for (int nf = 0; nf < 4; ++nf) {
      float* d = base + nf * 16;
      d[0] = acc[mf][nf][0] + bv.x;
      d[(size_t)L_] = acc[mf][nf][1] + bv.y;
      d[(size_t)2 * L_] = acc[mf][nf][2] + bv.z;
      d[(size_t)3 * L_] = acc[mf][nf][3] + bv.w;
    }
  }
}

// ---------------------------------------------------------------------------
// K3: depthwise conv(k=3,pad=1) + bias + SimpleGate, IN-PLACE over t1 first
// half + per-(b,c) mean for SCA. One block owns one (b,c) row (race-free).
// ---------------------------------------------------------------------------
__global__ __launch_bounds__(256) void dwgate_k(float* __restrict__ t1,
                                                float* __restrict__ p,
                                                const float* __restrict__ wd,
                                                const float* __restrict__ bd) {
  const int c = blockIdx.x;
  const int b = blockIdx.y;
  float* r1 = t1 + ((size_t)b * C2_ + c) * L_;
  float* r2 = t1 + ((size_t)b * C2_ + c + C_) * L_;
  const float w10 = wd[c * 3 + 0], w11 = wd[c * 3 + 1], w12 = wd[c * 3 + 2];
  const float w20 = wd[(c + C_) * 3 + 0], w21 = wd[(c + C_) * 3 + 1],
              w22 = wd[(c + C_) * 3 + 2];
  const float bd1 = bd[c], bd2 = bd[c + C_];
  const int tid = threadIdx.x;

  float gv[8][4];
  float sum = 0.f;
#pragma unroll
  for (int it = 0; it < 8; ++it) {
    int l = it * 1024 + tid * 4;
    float4 v1 = *(const float4*)(r1 + l);
    float4 v2 = *(const float4*)(r2 + l);
    float v1m = (l == 0) ? 0.f : r1[l - 1];
    float v1p = (l == L_ - 4) ? 0.f : r1[l + 4];
    float v2m = (l == 0) ? 0.f : r2[l - 1];
    float v2p = (l == L_ - 4) ? 0.f : r2[l + 4];
    float d1[4], d2[4];
    d1[0] = bd1 + w10 * v1m + w11 * v1.x + w12 * v1.y;
    d1[1] = bd1 + w10 * v1.x + w11 * v1.y + w12 * v1.z;
    d1[2] = bd1 + w10 * v1.y + w11 * v1.z + w12 * v1.w;
    d1[3] = bd1 + w10 * v1.z + w11 * v1.w + w12 * v1p;
    d2[0] = bd2 + w20 * v2m + w21 * v2.x + w22 * v2.y;
    d2[1] = bd2 + w20 * v2.x + w21 * v2.y + w22 * v2.z;
    d2[2] = bd2 + w20 * v2.y + w21 * v2.z + w22 * v2.w;
    d2[3] = bd2 + w20 * v2.z + w21 * v2.w + w22 * v2p;
#pragma unroll
    for (int j = 0; j < 4; ++j) {
      gv[it][j] = d1[j] * d2[j];
      sum += gv[it][j];
    }
  }
  __syncthreads();
#pragma unroll
  for (int it = 0; it < 8; ++it) {
    int l = it * 1024 + tid * 4;
    *(float4*)(r1 + l) = make_float4(gv[it][0], gv[it][1], gv[it][2], gv[it][3]);
  }
  __shared__ float red[256];
  red[tid] = sum;
  __syncthreads();
  for (int s = 128; s > 0; s >>= 1) {
    if (tid < s) red[tid] += red[tid + s];
    __syncthreads();
  }
  if (tid == 0) p[b * C_ + c] = red[0] * (1.f / L_);
}

// ---------------------------------------------------------------------------
// K4: SCA weights: wsca[b,o] = sigmoid(p @ ws^T + bs)
// ---------------------------------------------------------------------------
__global__ __launch_bounds__(256) void sca_k(const float* __restrict__ p,
                                             const float* __restrict__ ws,
                                             const float* __restrict__ bs,
                                             float* __restrict__ wsca) {
  int b = blockIdx.x, o = threadIdx.x;
  __shared__ float pp[C_];
  pp[o] = p[b * C_ + o];
  __syncthreads();
  float acc = bs[o];
  const float* wr = ws + (size_t)o * C_;
#pragma unroll 4
  for (int c = 0; c < C_; ++c) acc += pp[c] * wr[c];
  wsca[b * C_ + o] = 1.f / (1.f + expf(-acc));
}

// ---------------------------------------------------------------------------
// K5: pw2 as bf16x3-split MFMA GEMM; B = gate * wsca, epilogue adds b2 + x.
// ---------------------------------------------------------------------------
__global__ __launch_bounds__(256, 2) void pw2_mfma_k(
    const float* __restrict__ t1, const float* __restrict__ wsca,
    const short* __restrict__ w2h, const short* __restrict__ w2l,
    const float* __restrict__ b2, const float* __restrict__ x,
    float* __restrict__ out) {
  __shared__ short Ah[128 * LDK_], Al[128 * LDK_];
  __shared__ short Bh[128 * LDK_], Bl[128 * LDK_];
  const int g = blockIdx.x;
  const int chunk = g & 7, ii = g >> 3;          // ii in 0..255
  const int ob = ii & 1;
  const int blid = chunk * 128 + (ii >> 1);      // 0..1023
  const int b = blid >> 6, lb = blid & 63;
  const int o0 = ob * 128, l0 = lb * 128;
  const int tid = threadIdx.x;
  const int ar = tid >> 1, akq = (tid & 1) * 16;
  const int cq = (tid & 7) * 4, lq = (tid >> 3) * 4;
  const int lane = tid & 63, wv = tid >> 6;
  const int mb = (wv >> 1) * 64, nb = (wv & 1) * 64;
  const int fr = lane & 15, fko = (lane >> 4) * 8;

  const float* gb = t1 + (size_t)b * C2_ * L_ + l0 + lq;
  const float* scp = wsca + b * C_;

  f32x4 acc[4][4];
#pragma unroll
  for (int i = 0; i < 4; ++i)
#pragma unroll
    for (int j = 0; j < 4; ++j) acc[i][j] = 0.f;

  for (int kc = 0; kc < C_; kc += BK_) {
    const size_t aw = (size_t)(o0 + ar) * C_ + kc + akq;
    float4 a_h0 = *(const float4*)(w2h + aw);
    float4 a_h1 = *(const float4*)(w2h + aw + 8);
    float4 a_l0 = *(const float4*)(w2l + aw);
    float4 a_l1 = *(const float4*)(w2l + aw + 8);
    float4 sc4 = *(const float4*)(scp + kc + cq);
    float sc[4] = {sc4.x, sc4.y, sc4.z, sc4.w};
    float yv[4][4];
#pragma unroll
    for (int i = 0; i < 4; ++i) {
      float4 xv = *(const float4*)(gb + (size_t)(kc + cq + i) * L_);
      yv[i][0] = xv.x * sc[i];
      yv[i][1] = xv.y * sc[i];
      yv[i][2] = xv.z * sc[i];
      yv[i][3] = xv.w * sc[i];
    }
    __syncthreads();
    *(float4*)&Ah[ar * LDK_ + akq] = a_h0;
    *(float4*)&Ah[ar * LDK_ + akq + 8] = a_h1;
    *(float4*)&Al[ar * LDK_ + akq] = a_l0;
    *(float4*)&Al[ar * LDK_ + akq + 8] = a_l1;
#pragma unroll
    for (int j = 0; j < 4; ++j) {
      short4 hh, ll;
      hh.x = f2bf(yv[0][j]); ll.x = f2bf(yv[0][j] - bf2f(hh.x));
      hh.y = f2bf(yv[1][j]); ll.y = f2bf(yv[1][j] - bf2f(hh.y));
      hh.z = f2bf(yv[2][j]); ll.z = f2bf(yv[2][j] - bf2f(hh.z));
      hh.w = f2bf(yv[3][j]); ll.w = f2bf(yv[3][j] - bf2f(hh.w));
      *(short4*)&Bh[(lq + j) * LDK_ + cq] = hh;
      *(short4*)&Bl[(lq + j) * LDK_ + cq] = ll;
    }
    __syncthreads();
    bf16x8 fah[4], fal[4], fbh[4], fbl[4];
#pragma unroll
    for (int f = 0; f < 4; ++f) {
      fah[f] = *(const bf16x8*)&Ah[(mb + f * 16 + fr) * LDK_ + fko];
      fal[f] = *(const bf16x8*)&Al[(mb + f * 16 + fr) * LDK_ + fko];
      fbh[f] = *(const bf16x8*)&Bh[(nb + f * 16 + fr) * LDK_ + fko];
      fbl[f] = *(const bf16x8*)&Bl[(nb + f * 16 + fr) * LDK_ + fko];
    }
#pragma unroll
    for (int mf = 0; mf < 4; ++mf)
#pragma unroll
      for (int nf = 0; nf < 4; ++nf) {
        f32x4 c = acc[mf][nf];
        c = __builtin_amdgcn_mfma_f32_16x16x32_bf16(fah[mf], fbh[nf], c, 0, 0, 0);
        c = __builtin_amdgcn_mfma_f32_16x16x32_bf16(fah[mf], fbl[nf], c, 0, 0, 0);
        c = __builtin_amdgcn_mfma_f32_16x16x32_bf16(fal[mf], fbh[nf], c, 0, 0, 0);
        acc[mf][nf] = c;
      }
  }
#pragma unroll
  for (int mf = 0; mf < 4; ++mf) {
    const int orow = o0 + mb + mf * 16 + ((lane >> 4) << 2);
    const float4 bv = *(const float4*)(b2 + orow);
    const float* xr = x + ((size_t)b * C_ + orow) * L_ + l0 + nb + fr;
    float* d0 = out + ((size_t)b * C_ + orow) * L_ + l0 + nb + fr;
#pragma unroll
    for (int nf = 0; nf < 4; ++nf) {
      const float* xq = xr + nf * 16;
      float* d = d0 + nf * 16;
      d[0] = acc[mf][nf][0] + bv.x + xq[0];
      d[(size_t)L_] = acc[mf][nf][1] + bv.y + xq[(size_t)L_];
      d[(size_t)2 * L_] = acc[mf][nf][2] + bv.z + xq[(size_t)2 * L_];
      d[(size_t)3 * L_] = acc[mf][nf][3] + bv.w + xq[(size_t)3 * L_];
    }
  }
}

// ---------------------------------------------------------------------------
// Workspace layout (floats then shorts):
//   t1   : B*C2*L = 67,108,864 f   (256 MiB)
//   mu,rs: B*L each; p,wsca: B*C each
//   w1h/w1l: 131072 shorts each; w2h/w2l: 65536 shorts each  (~768 KiB)
// ---------------------------------------------------------------------------
extern "C" void kernel_launch(void* const* d_in, const int* in_sizes, int n_in,
                              void* d_out, int out_size, void* d_ws,
                              size_t ws_size, hipStream_t stream) {
  const float* x = (const float*)d_in[0];
  const float* gamma = (const float*)d_in[1];
  const float* beta = (const float*)d_in[2];
  const float* w1 = (const float*)d_in[3];
  const float* b1 = (const float*)d_in[4];
  const float* wd = (const float*)d_in[5];
  const float* bd = (const float*)d_in[6];
  const float* ws = (const float*)d_in[7];
  const float* bs = (const float*)d_in[8];
  const float* w2 = (const float*)d_in[9];
  const float* b2 = (const float*)d_in[10];
  float* out = (float*)d_out;

  float* t1 = (float*)d_ws;
  float* muv = t1 + (size_t)B_ * C2_ * L_;
  float* rsv = muv + (size_t)B_ * L_;
  float* p = rsv + (size_t)B_ * L_;
  float* wsca = p + B_ * C_;
  short* w1h = (short*)(wsca + B_ * C_);
  short* w1l = w1h + C2_ * C_;
  short* w2h = w1l + C2_ * C_;
  short* w2l = w2h + C_ * C_;

  wprep_k<<<dim3((C2_ * C_ + C_ * C_) / 256), 256, 0, stream>>>(w1, w2, w1h,
                                                                w1l, w2h, w2l);
  ln_stats_k<<<dim3(B_ * L_ / 4 / 128), 128, 0, stream>>>(x, muv, rsv);
  pw1_mfma_k<<<dim3(4 * 64 * B_), 256, 0, stream>>>(x, muv, rsv, gamma, beta,
                                                    w1h, w1l, b1, t1);
  dwgate_k<<<dim3(C_, B_), 256, 0, stream>>>(t1, p, wd, bd);
  sca_k<<<dim3(B_), 256, 0, stream>>>(p, ws, bs, wsca);
  pw2_mfma_k<<<dim3(2 * 64 * B_), 256, 0, stream>>>(t1, wsca, w2h, w2l, b2, x,
                                                    out);
}

// Round 6
// 523.628 us; speedup vs baseline: 1.7758x; 1.1761x over previous
//
#include <hip/hip_runtime.h>
#include <cstddef>
#include <cstdint>

#define B_ 16
#define C_ 256
#define C2_ 512
#define L_ 8192
#define EPS_ 1e-5f

typedef __attribute__((ext_vector_type(8))) short bf16x8;  // 8 bf16 = 4 VGPR
typedef __attribute__((ext_vector_type(4))) float f32x4;

static __device__ __forceinline__ unsigned short f2bf(float f) {  // RTNE
  unsigned u = __builtin_bit_cast(unsigned, f);
  unsigned r = (u + 0x7fffu + ((u >> 16) & 1u)) >> 16;
  return (unsigned short)r;
}
static __device__ __forceinline__ float bf2f(unsigned short h) {
  unsigned u = ((unsigned)h) << 16;
  return __builtin_bit_cast(float, u);
}
// async global->LDS, 16B per lane. LDS dest = wave-uniform base + lane*16.
static __device__ __forceinline__ void gl_lds16(const unsigned short* g, short* l) {
  __builtin_amdgcn_global_load_lds(
      (const __attribute__((address_space(1))) unsigned int*)g,
      (__attribute__((address_space(3))) unsigned int*)l, 16, 0, 0);
}

// ---------------------------------------------------------------------------
// P0: split w1 into bf16 hi/lo (2-term weight emulation).
// ---------------------------------------------------------------------------
__global__ __launch_bounds__(256) void prep_w_k(const float* __restrict__ w1,
                                                unsigned short* __restrict__ w1h,
                                                unsigned short* __restrict__ w1l) {
  int i = (blockIdx.x * 256 + threadIdx.x) * 4;  // 131072 elems, grid 128
  float4 f = *(const float4*)(w1 + i);
  ushort4 h, l;
  h.x = f2bf(f.x); l.x = f2bf(f.x - bf2f(h.x));
  h.y = f2bf(f.y); l.y = f2bf(f.y - bf2f(h.y));
  h.z = f2bf(f.z); l.z = f2bf(f.z - bf2f(h.z));
  h.w = f2bf(f.w); l.w = f2bf(f.w - bf2f(h.w));
  *(ushort4*)(w1h + i) = h;
  *(ushort4*)(w1l + i) = l;
}

// ---------------------------------------------------------------------------
// K1: fused LN-stats + normalize + transpose + bf16: yt[b][l][c].
// Block: 64 l x 256 c tile.
// ---------------------------------------------------------------------------
__global__ __launch_bounds__(256, 2) void ynormT_k(const float* __restrict__ x,
                                                   const float* __restrict__ gamma,
                                                   const float* __restrict__ beta,
                                                   unsigned short* __restrict__ yt) {
  __shared__ float Xs[C_][65];   // padded: bank = (c + l) % 32
  __shared__ float redS[64][4], redQ[64][4];
  __shared__ float smu[64], srs[64];
  __shared__ float sg[C_], sb[C_];
  const int lt = blockIdx.x, b = blockIdx.y;
  const int t = threadIdx.x;
  const int l0 = lt * 64;
  sg[t] = gamma[t];
  sb[t] = beta[t];
  const float* xr = x + ((size_t)b * C_ + t) * L_ + l0;  // row c = t
#pragma unroll
  for (int i = 0; i < 16; ++i) {
    float4 v = *(const float4*)(xr + i * 4);
    Xs[t][i * 4 + 0] = v.x;
    Xs[t][i * 4 + 1] = v.y;
    Xs[t][i * 4 + 2] = v.z;
    Xs[t][i * 4 + 3] = v.w;
  }
  __syncthreads();
  {
    int lq = t & 63, part = t >> 6;
    float s = 0.f, q = 0.f;
#pragma unroll 8
    for (int i = 0; i < 64; ++i) {
      float v = Xs[part * 64 + i][lq];
      s += v;
      q += v * v;
    }
    redS[lq][part] = s;
    redQ[lq][part] = q;
  }
  __syncthreads();
  if (t < 64) {
    float s = redS[t][0] + redS[t][1] + redS[t][2] + redS[t][3];
    float q = redQ[t][0] + redQ[t][1] + redQ[t][2] + redQ[t][3];
    float m = s * (1.f / C_);
    float var = q * (1.f / C_) - m * m;
    smu[t] = m;
    srs[t] = rsqrtf(var + EPS_);
  }
  __syncthreads();
  {
    int lq = t >> 2, c0 = (t & 3) * 64;
    float m = smu[lq], r = srs[lq];
    unsigned pk[32];
#pragma unroll
    for (int i = 0; i < 32; ++i) {
      int c = c0 + i * 2;
      float y0 = (Xs[c][lq] - m) * r * sg[c] + sb[c];
      float y1 = (Xs[c + 1][lq] - m) * r * sg[c + 1] + sb[c + 1];
      pk[i] = (unsigned)f2bf(y0) | ((unsigned)f2bf(y1) << 16);
    }
    unsigned* dst = (unsigned*)(yt + ((size_t)b * L_ + l0 + lq) * C_ + c0);
#pragma unroll
    for (int i = 0; i < 8; ++i)
      *(uint4*)(dst + i * 4) = make_uint4(pk[i * 4], pk[i * 4 + 1], pk[i * 4 + 2], pk[i * 4 + 3]);
  }
}

// ---------------------------------------------------------------------------
// K2: pw1 GEMM (quarter of batch). t1q[bl][l][o] fp32 = yt @ w1^T + b1.
// A = yt rows l (single bf16), B = w1 rows o (hi/lo). 2-term MFMA.
// Block 256 l x 128 o, 4 waves (2x2), wave tile 128 l x 64 o.
// LDS rows are 64B; sigma-swizzle sigma(r)=(r>>1)&3 applied via global source
// slot permutation (linear LDS dest for global_load_lds), undone on ds_read.
// ---------------------------------------------------------------------------
__global__ __launch_bounds__(256, 2) void pw1_mfma_k(
    const unsigned short* __restrict__ yt, const unsigned short* __restrict__ w1h,
    const unsigned short* __restrict__ w1l, const float* __restrict__ b1,
    float* __restrict__ t1q, int bq) {
  __shared__ __align__(16) short As[256 * 32];
  __shared__ __align__(16) short Bh[128 * 32];
  __shared__ __align__(16) short Bl[128 * 32];
  const int u = blockIdx.x;
  const int r = (u & 7) * 64 + (u >> 3);  // 512 = 8*64, bijective XCD chunking
  const int ot = r & 3;
  const int lt = (r >> 2) & 31;
  const int bl_ = r >> 7;  // 0..3
  const int b = bq * 4 + bl_;
  const int o0 = ot * 128, l0 = lt * 256;
  const int tid = threadIdx.x;
  const int lane = tid & 63, wv = tid >> 6;
  const int wl = wv >> 1, wo = wv & 1;
  const int fr = lane & 15;
  const int laneoff = fr * 64 + (((lane >> 4) ^ ((fr >> 1) & 3)) << 4);  // bytes
  const int srow = lane >> 2;                       // staging row-in-16
  const int sslot = (lane & 3) ^ ((lane >> 3) & 3); // global slot = p ^ sigma(row)
  const unsigned short* ybase = yt + ((size_t)b * L_ + l0) * C_;

  f32x4 acc[8][4];
#pragma unroll
  for (int i = 0; i < 8; ++i)
#pragma unroll
    for (int j = 0; j < 4; ++j) acc[i][j] = 0.f;

  for (int kc = 0; kc < C_; kc += 32) {
    __syncthreads();  // prior frag reads done before overwrite
    if (wv < 2) {
#pragma unroll
      for (int i = 0; i < 8; ++i) {
        int row0 = wv * 128 + i * 16;
        const unsigned short* gp = ybase + (size_t)(row0 + srow) * C_ + kc + sslot * 8;
        gl_lds16(gp, As + row0 * 32);
      }
    } else {
      const unsigned short* wsrc = (wv == 2) ? w1h : w1l;
      short* dst = (wv == 2) ? Bh : Bl;
#pragma unroll
      for (int i = 0; i < 8; ++i) {
        int row0 = i * 16;
        const unsigned short* gp = wsrc + (size_t)(o0 + row0 + srow) * C_ + kc + sslot * 8;
        gl_lds16(gp, dst + row0 * 32);
      }
    }
    __syncthreads();  // vmcnt(0) drained by compiler before barrier

    bf16x8 bhf[4], blf[4];
#pragma unroll
    for (int nf = 0; nf < 4; ++nf) {
      int rb = (wo * 64 + nf * 16) * 64;
      bhf[nf] = *(const bf16x8*)((const char*)Bh + rb + laneoff);
      blf[nf] = *(const bf16x8*)((const char*)Bl + rb + laneoff);
    }
#pragma unroll
    for (int mh = 0; mh < 2; ++mh) {
      bf16x8 af[4];
#pragma unroll
      for (int m = 0; m < 4; ++m) {
        int ra = (wl * 128 + (mh * 4 + m) * 16) * 64;
        af[m] = *(const bf16x8*)((const char*)As + ra + laneoff);
      }
#pragma unroll
      for (int nf = 0; nf < 4; ++nf)
#pragma unroll
        for (int m = 0; m < 4; ++m) {
          f32x4 c = acc[mh * 4 + m][nf];
          c = __builtin_amdgcn_mfma_f32_16x16x32_bf16(af[m], bhf[nf], c, 0, 0, 0);
          c = __builtin_amdgcn_mfma_f32_16x16x32_bf16(af[m], blf[nf], c, 0, 0, 0);
          acc[mh * 4 + m][nf] = c;
        }
    }
  }
  // D: row=(lane>>4)*4+reg = l (A rows), col=lane&15 = o (B rows)
  const int lr = lane >> 4;
#pragma unroll
  for (int nf = 0; nf < 4; ++nf) {
    int o = o0 + wo * 64 + nf * 16 + fr;
    float bias = b1[o];
#pragma unroll
    for (int mf = 0; mf < 8; ++mf) {
      int lb = l0 + wl * 128 + mf * 16 + lr * 4;
      float* dp = t1q + ((size_t)bl_ * L_ + lb) * C2_ + o;
#pragma unroll
      for (int j = 0; j < 4; ++j) dp[(size_t)j * C2_] = acc[mf][nf][j] + bias;
    }
  }
}

// ---------------------------------------------------------------------------
// K3: depthwise conv(3,pad1)+bias+SimpleGate on t1q[l][o] -> gt[b][l][c] bf16,
// + per-(b,c) partial sums. Thread = channel pair (c, c+256), rolling rows.
// ---------------------------------------------------------------------------
__global__ __launch_bounds__(256) void dwgate_k(const float* __restrict__ t1q,
                                                const float* __restrict__ wd,
                                                const float* __restrict__ bd,
                                                unsigned short* __restrict__ gt,
                                                float* __restrict__ pp, int bq) {
  const int ch = blockIdx.x;   // 64 chunks of 128 l
  const int bl_ = blockIdx.y;  // 0..3
  const int b = bq * 4 + bl_;
  const int c = threadIdx.x;
  const float w10 = wd[c * 3], w11 = wd[c * 3 + 1], w12 = wd[c * 3 + 2];
  const float w20 = wd[(c + C_) * 3], w21 = wd[(c + C_) * 3 + 1], w22 = wd[(c + C_) * 3 + 2];
  const float b1d = bd[c], b2d = bd[c + C_];
  const int l0 = ch * 128;
  const float* base = t1q + (size_t)bl_ * L_ * C2_;
  float a1p = (l0 == 0) ? 0.f : base[(size_t)(l0 - 1) * C2_ + c];
  float a2p = (l0 == 0) ? 0.f : base[(size_t)(l0 - 1) * C2_ + c + C_];
  float a1c = base[(size_t)l0 * C2_ + c];
  float a2c = base[(size_t)l0 * C2_ + c + C_];
  float sum = 0.f;
  unsigned short* grow = gt + ((size_t)b * L_ + l0) * C_ + c;
#pragma unroll 8
  for (int i = 0; i < 128; ++i) {
    int gl = l0 + i;
    float a1n = (gl == L_ - 1) ? 0.f : base[(size_t)(gl + 1) * C2_ + c];
    float a2n = (gl == L_ - 1) ? 0.f : base[(size_t)(gl + 1) * C2_ + c + C_];
    float d1 = fmaf(w10, a1p, fmaf(w11, a1c, fmaf(w12, a1n, b1d)));
    float d2 = fmaf(w20, a2p, fmaf(w21, a2c, fmaf(w22, a2n, b2d)));
    float g = d1 * d2;
    sum += g;
    grow[(size_t)i * C_] = f2bf(g);
    a1p = a1c; a1c = a1n;
    a2p = a2c; a2c = a2n;
  }
  pp[((size_t)b * 64 + ch) * C_ + c] = sum;
}

// ---------------------------------------------------------------------------
// K4: SCA: p -> sigmoid(p@ws^T+bs) -> w2s[b][o][c] = w2*s (hi/lo split).
// ---------------------------------------------------------------------------
__global__ __launch_bounds__(256) void sca_w2_k(const float* __restrict__ pp,
                                                const float* __restrict__ ws,
                                                const float* __restrict__ bs,
                                                const float* __restrict__ w2,
                                                unsigned short* __restrict__ w2sh,
                                                unsigned short* __restrict__ w2sl) {
  const int b = blockIdx.x >> 3, og = blockIdx.x & 7;
  const int c = threadIdx.x;
  __shared__ float sp[C_], ss[C_];
  float s = 0.f;
  for (int ch = 0; ch < 64; ++ch) s += pp[((size_t)b * 64 + ch) * C_ + c];
  sp[c] = s * (1.f / L_);
  __syncthreads();
  float acc = bs[c];
  const float* wr = ws + (size_t)c * C_;
#pragma unroll 4
  for (int k = 0; k < C_; ++k) acc += wr[k] * sp[k];
  ss[c] = 1.f / (1.f + expf(-acc));
  __syncthreads();
  for (int o = og * 32; o < og * 32 + 32; ++o) {
    float v = w2[(size_t)o * C_ + c] * ss[c];
    unsigned short h = f2bf(v);
    w2sh[((size_t)b * C_ + o) * C_ + c] = h;
    w2sl[((size_t)b * C_ + o) * C_ + c] = f2bf(v - bf2f(h));
  }
}

// ---------------------------------------------------------------------------
// K5: pw2 GEMM: out[b][o][l] = x + b2 + w2s[b] @ gt[b].
// A = w2s rows o (hi/lo), B = gt rows l (single). Block 128 o x 256 l.
// ---------------------------------------------------------------------------
__global__ __launch_bounds__(256, 2) void pw2_mfma_k(
    const unsigned short* __restrict__ gt, const unsigned short* __restrict__ w2sh,
    const unsigned short* __restrict__ w2sl, const float* __restrict__ b2,
    const float* __restrict__ x, float* __restrict__ out) {
  __shared__ __align__(16) short Ah[128 * 32];
  __shared__ __align__(16) short Al[128 * 32];
  __shared__ __align__(16) short Bs[256 * 32];
  const int u = blockIdx.x;
  const int r = (u & 7) * 128 + (u >> 3);  // 1024 = 8*128
  const int ot = r & 1;
  const int lt = (r >> 1) & 31;
  const int b = r >> 6;
  const int o0 = ot * 128, l0 = lt * 256;
  const int tid = threadIdx.x;
  const int lane = tid & 63, wv = tid >> 6;
  const int wo = wv >> 1, wln = wv & 1;  // wave tile 64 o x 128 l
  const int fr = lane & 15;
  const int laneoff = fr * 64 + (((lane >> 4) ^ ((fr >> 1) & 3)) << 4);
  const int srow = lane >> 2;
  const int sslot = (lane & 3) ^ ((lane >> 3) & 3);
  const unsigned short* gbase = gt + ((size_t)b * L_ + l0) * C_;
  const unsigned short* ahb = w2sh + (size_t)b * C_ * C_;
  const unsigned short* alb = w2sl + (size_t)b * C_ * C_;

  f32x4 acc[4][8];
#pragma unroll
  for (int i = 0; i < 4; ++i)
#pragma unroll
    for (int j = 0; j < 8; ++j) acc[i][j] = 0.f;

  for (int kc = 0; kc < C_; kc += 32) {
    __syncthreads();
    if (wv < 2) {
      const unsigned short* src = (wv == 0) ? ahb : alb;
      short* dst = (wv == 0) ? Ah : Al;
#pragma unroll
      for (int i = 0; i < 8; ++i) {
        int row0 = i * 16;
        const unsigned short* gp = src + (size_t)(o0 + row0 + srow) * C_ + kc + sslot * 8;
        gl_lds16(gp, dst + row0 * 32);
      }
    } else {
#pragma unroll
      for (int i = 0; i < 8; ++i) {
        int row0 = (wv - 2) * 128 + i * 16;
        const unsigned short* gp = gbase + (size_t)(row0 + srow) * C_ + kc + sslot * 8;
        gl_lds16(gp, Bs + row0 * 32);
      }
    }
    __syncthreads();

    bf16x8 ah[4], al[4];
#pragma unroll
    for (int mf = 0; mf < 4; ++mf) {
      int ra = (wo * 64 + mf * 16) * 64;
      ah[mf] = *(const bf16x8*)((const char*)Ah + ra + laneoff);
      al[mf] = *(const bf16x8*)((const char*)Al + ra + laneoff);
    }
#pragma unroll
    for (int nh = 0; nh < 2; ++nh) {
      bf16x8 bf_[4];
#pragma unroll
      for (int n = 0; n < 4; ++n) {
        int rb = (wln * 128 + (nh * 4 + n) * 16) * 64;
        bf_[n] = *(const bf16x8*)((const char*)Bs + rb + laneoff);
      }
#pragma unroll
      for (int n = 0; n < 4; ++n)
#pragma unroll
        for (int mf = 0; mf < 4; ++mf) {
          f32x4 c = acc[mf][nh * 4 + n];
          c = __builtin_amdgcn_mfma_f32_16x16x32_bf16(ah[mf], bf_[n], c, 0, 0, 0);
          c = __builtin_amdgcn_mfma_f32_16x16x32_bf16(al[mf], bf_[n], c, 0, 0, 0);
          acc[mf][nh * 4 + n] = c;
        }
    }
  }
  // D: row = o (A rows), col = l (B rows)
  const int lr = lane >> 4;
#pragma unroll
  for (int mf = 0; mf < 4; ++mf) {
    int ob = o0 + wo * 64 + mf * 16 + lr * 4;
    float4 b2v = *(const float4*)(b2 + ob);
    float bb[4] = {b2v.x, b2v.y, b2v.z, b2v.w};
#pragma unroll
    for (int nf = 0; nf < 8; ++nf) {
      int l = l0 + wln * 128 + nf * 16 + fr;
#pragma unroll
      for (int j = 0; j < 4; ++j) {
        size_t idx = ((size_t)b * C_ + ob + j) * L_ + l;
        out[idx] = acc[mf][nf][j] + bb[j] + x[idx];
      }
    }
  }
}

// ---------------------------------------------------------------------------
// Workspace (bytes):
//   yt   : 16*8192*256*2      = 67,108,864
//   t1q  : 4*8192*512*4       = 67,108,864   (quarter of batch, fp32, reused x4)
//   gt   : 16*8192*256*2      = 67,108,864
//   pp   : 16*64*256*4        = 1,048,576
//   w1h/w1l : 262,144 each;  w2sh/w2sl : 2,097,152 each
// total ~= 207 MB (< proven 257 MB)
// ---------------------------------------------------------------------------
extern "C" void kernel_launch(void* const* d_in, const int* in_sizes, int n_in,
                              void* d_out, int out_size, void* d_ws,
                              size_t ws_size, hipStream_t stream) {
  const float* x = (const float*)d_in[0];
  const float* gamma = (const float*)d_in[1];
  const float* beta = (const float*)d_in[2];
  const float* w1 = (const float*)d_in[3];
  const float* b1 = (const float*)d_in[4];
  const float* wd = (const float*)d_in[5];
  const float* bd = (const float*)d_in[6];
  const float* ws = (const float*)d_in[7];
  const float* bs = (const float*)d_in[8];
  const float* w2 = (const float*)d_in[9];
  const float* b2 = (const float*)d_in[10];
  float* out = (float*)d_out;

  char* w = (char*)d_ws;
  unsigned short* yt = (unsigned short*)w;
  float* t1q = (float*)(w + 67108864);
  unsigned short* gt = (unsigned short*)(w + 2 * 67108864);
  float* pp = (float*)(w + 3 * 67108864);
  unsigned short* w1h = (unsigned short*)(w + 3 * 67108864 + 1048576);
  unsigned short* w1l = w1h + 131072;
  unsigned short* w2sh = w1l + 131072;
  unsigned short* w2sl = w2sh + 1048576;

  prep_w_k<<<128, 256, 0, stream>>>(w1, w1h, w1l);
  ynormT_k<<<dim3(128, 16), 256, 0, stream>>>(x, gamma, beta, yt);
  for (int q = 0; q < 4; ++q) {
    pw1_mfma_k<<<512, 256, 0, stream>>>(yt, w1h, w1l, b1, t1q, q);
    dwgate_k<<<dim3(64, 4), 256, 0, stream>>>(t1q, wd, bd, gt, pp, q);
  }
  sca_w2_k<<<128, 256, 0, stream>>>(pp, ws, bs, w2, w2sh, w2sl);
  pw2_mfma_k<<<1024, 256, 0, stream>>>(gt, w2sh, w2sl, b2, x, out);
}